// Round 3
// baseline (942.090 us; speedup 1.0000x reference)
//
#include <hip/hip_runtime.h>

#define NTOTAL 100000
#define NNODES 16384
#define NPB 4                 // nodes per block
#define K 32
#define S 16
#define D 190
#define E 64
#define NREL 3
#define NQ (NPB * NREL)       // 12 stage/compute phases per block
#define ROWB 768              // staged bytes per row (192 floats incl. 2 pad)
#define BUFB (K * ROWB)       // 24576 B per buffer

typedef const __attribute__((address_space(1))) unsigned int* gptr_t;
typedef __attribute__((address_space(3))) unsigned int* lptr_t;

// ---------- helper: inverse L2 norms of all feature rows ----------
__global__ __launch_bounds__(256) void norms_kernel(const float* __restrict__ features,
                                                    float* __restrict__ invn) {
    const int row  = blockIdx.x * 4 + (threadIdx.x >> 6);
    const int lane = threadIdx.x & 63;
    if (row >= NTOTAL) return;
    const float2* rp = (const float2*)(features + (size_t)row * D);
    float2 a = rp[lane];
    float ss = fmaf(a.x, a.x, a.y * a.y);
    if (lane < 95 - 64) {
        float2 b = rp[64 + lane];
        ss = fmaf(b.x, b.x, fmaf(b.y, b.y, ss));
    }
    #pragma unroll
    for (int off = 32; off; off >>= 1) ss += __shfl_xor(ss, off, 64);
    if (lane == 0) invn[row] = 1.0f / sqrtf(ss);
}

// ---------- fused main kernel: one block per 4 nodes, async LDS pipeline ----------
template <bool HAVE_NORMS>
__global__ __launch_bounds__(256) void interagg_fused(
    const float* __restrict__ features,   // [N_TOTAL, D]
    const int*   __restrict__ nodes,      // [N]
    const int*   __restrict__ neigh1,     // [N, K]
    const int*   __restrict__ neigh2,
    const int*   __restrict__ neigh3,
    const float* __restrict__ weight,     // [D, E]
    const float* __restrict__ avec,       // [2E]
    const float* __restrict__ invn,       // [N_TOTAL] or nullptr
    float*       __restrict__ out)        // [N, E]
{
    __shared__ __align__(16) unsigned char s_raw[2 * BUFB];   // 48 KB row buffers
    __shared__ __align__(16) float s_center[NPB * 192];       // 3 KB (dims 190,191 garbage, masked)
    __shared__ int   s_idx[NQ * K];                           // 1.5 KB
    __shared__ float s_rmean[NREL][192];
    __shared__ float s_sim[K];
    __shared__ int   s_selslot[S];
    __shared__ float s_h[4][E];
    __shared__ float s_dots[4];

    const int t    = threadIdx.x;
    const int lane = t & 63;
    const int wave = t >> 6;
    const int nb   = blockIdx.x * NPB;

    // ---- prologue: neighbor indices -> LDS ----
    for (int f = t; f < NQ * K; f += 256) {
        const int q = f >> 5, k = f & 31;
        const int j = q / 3, rr = q % 3;
        const int* np = (rr == 0) ? neigh1 : (rr == 1) ? neigh2 : neigh3;
        s_idx[f] = np[(nb + j) * K + k];
    }
    asm volatile("s_waitcnt lgkmcnt(0)" ::: "memory");
    __builtin_amdgcn_s_barrier();

    // staging helper: 32 rows = 1536 16B-chunks, 24 wave-instrs (6 per wave),
    // LDS dest is wave-uniform base + lane*16 (linear), global addr per-lane.
    auto stage_rel = [&](int q, int bsel) {
        const int* idxq = s_idx + q * K;
        #pragma unroll
        for (int i = 0; i < 6; ++i) {
            const int m   = (wave * 6 + i) * 64 + lane;   // flat chunk 0..1535
            const int row = (m * 683) >> 15;              // m / 48
            const int c   = m - row * 48;
            const int rid = idxq[row];
            const float* g = features + (size_t)rid * D + c * 4;
            unsigned char* lp = s_raw + bsel * BUFB + (wave * 6 + i) * 1024;
            __builtin_amdgcn_global_load_lds((gptr_t)g, (lptr_t)lp, 16, 0, 0);
        }
    };

    // ---- prologue staging: centers (3 instrs, waves 0..2) + relation 0 ----
    if (wave < 3) {
        const int m   = wave * 64 + lane;                 // 0..191
        const int row = (m * 683) >> 15;
        const int c   = m - row * 48;
        const float* g = features + (size_t)nodes[nb + row] * D + c * 4;
        unsigned char* lp = (unsigned char*)s_center + wave * 1024;
        __builtin_amdgcn_global_load_lds((gptr_t)g, (lptr_t)lp, 16, 0, 0);
    }
    stage_rel(0, 0);
    float invn_next = 0.f;
    if (HAVE_NORMS && (t & 7) == 0) invn_next = invn[s_idx[t >> 3]];

    // ---- main pipeline: stage(q+1) || compute(q) ----
    for (int q = 0; q < NQ; ++q) {
        const int bsel = q & 1;
        const float invn_cur = invn_next;

        if (q < NQ - 1) {
            stage_rel(q + 1, bsel ^ 1);
            if (HAVE_NORMS && (t & 7) == 0)
                invn_next = invn[s_idx[(q + 1) * K + (t >> 3)]];
            // drain: all older loads (prev stage + prev invn [+ centers]),
            // keep the 6 just-issued stages (+1 invn) in flight.
            if constexpr (HAVE_NORMS)
                asm volatile("s_waitcnt vmcnt(7) lgkmcnt(0)" ::: "memory");
            else
                asm volatile("s_waitcnt vmcnt(6) lgkmcnt(0)" ::: "memory");
        } else {
            asm volatile("s_waitcnt vmcnt(0) lgkmcnt(0)" ::: "memory");
        }
        __builtin_amdgcn_sched_barrier(0);
        __builtin_amdgcn_s_barrier();

        // ---- sims: 8 threads per row, float4 LDS reads (bank-quad clean) ----
        {
            const int row = t >> 3, g = t & 7;
            const float* rbase = (const float*)(s_raw + bsel * BUFB + row * ROWB);
            const float* cbase = s_center + (q / 3) * 192;
            float dot = 0.f, ss = 0.f;
            #pragma unroll
            for (int jj = 0; jj < 6; ++jj) {
                const int c = g + 8 * jj;
                float4 rv = *(const float4*)(rbase + c * 4);
                const float4 cv = *(const float4*)(cbase + c * 4);
                if (jj == 5 && g == 7) { rv.z = 0.f; rv.w = 0.f; }  // dims 190,191
                dot = fmaf(rv.x, cv.x, fmaf(rv.y, cv.y,
                      fmaf(rv.z, cv.z, fmaf(rv.w, cv.w, dot))));
                if (!HAVE_NORMS)
                    ss = fmaf(rv.x, rv.x, fmaf(rv.y, rv.y,
                         fmaf(rv.z, rv.z, fmaf(rv.w, rv.w, ss))));
            }
            dot += __shfl_xor(dot, 1, 64);
            dot += __shfl_xor(dot, 2, 64);
            dot += __shfl_xor(dot, 4, 64);
            if (!HAVE_NORMS) {
                ss += __shfl_xor(ss, 1, 64);
                ss += __shfl_xor(ss, 2, 64);
                ss += __shfl_xor(ss, 4, 64);
            }
            if (g == 0)
                s_sim[row] = HAVE_NORMS ? dot * invn_cur : dot / sqrtf(ss);
        }
        asm volatile("s_waitcnt lgkmcnt(0)" ::: "memory");
        __builtin_amdgcn_s_barrier();

        // ---- top-S by rank (ties -> lower index, matches lax.top_k) ----
        if (t < K) {
            const float sk = s_sim[t];
            int rank = 0;
            #pragma unroll
            for (int jx = 0; jx < K; ++jx) {
                const float sj = s_sim[jx];
                rank += (sj > sk) || (sj == sk && jx < t);
            }
            if (rank < S) s_selslot[rank] = t;
        }
        asm volatile("s_waitcnt lgkmcnt(0)" ::: "memory");
        __builtin_amdgcn_s_barrier();

        // ---- masked mean + relu from the SAME LDS copy (no re-gather) ----
        if (t < 95) {
            float2 acc = make_float2(0.f, 0.f);
            #pragma unroll
            for (int jx = 0; jx < S; ++jx) {
                const int slot = s_selslot[jx];
                const float2 v = *(const float2*)(s_raw + bsel * BUFB + slot * ROWB + t * 8);
                acc.x += v.x; acc.y += v.y;
            }
            const int rr = q % 3;
            s_rmean[rr][2 * t]     = fmaxf(acc.x * (1.f / 16), 0.f);
            s_rmean[rr][2 * t + 1] = fmaxf(acc.y * (1.f / 16), 0.f);
        }

        // ---- node epilogue after its 3 relations ----
        if ((q % 3) == 2) {
            asm volatile("s_waitcnt lgkmcnt(0)" ::: "memory");
            __builtin_amdgcn_s_barrier();
            const int j = q / 3;
            // h[v] = vec_v @ W  (wave 0: center, waves 1-3: relations)
            {
                const float* vec = (wave == 0) ? (s_center + j * 192) : s_rmean[wave - 1];
                float a0 = 0.f, a1 = 0.f;
                #pragma unroll 2
                for (int d = 0; d < D; d += 2) {
                    a0 = fmaf(vec[d],     weight[d * E + lane],       a0);
                    a1 = fmaf(vec[d + 1], weight[(d + 1) * E + lane], a1);
                }
                s_h[wave][lane] = a0 + a1;
            }
            asm volatile("s_waitcnt lgkmcnt(0)" ::: "memory");
            __builtin_amdgcn_s_barrier();
            // attention dots
            {
                const float* av = (wave == 0) ? avec : (avec + E);
                float val = s_h[wave][lane] * av[lane];
                #pragma unroll
                for (int off = 32; off; off >>= 1) val += __shfl_xor(val, off, 64);
                if (lane == 0) s_dots[wave] = val;
            }
            asm volatile("s_waitcnt lgkmcnt(0)" ::: "memory");
            __builtin_amdgcn_s_barrier();
            // leaky-relu, softmax over 3 relations, aggregate, relu, store
            if (t < E) {
                const float d0 = s_dots[0];
                float e1 = d0 + s_dots[1];
                float e2 = d0 + s_dots[2];
                float e3 = d0 + s_dots[3];
                e1 = (e1 >= 0.f) ? e1 : 0.2f * e1;
                e2 = (e2 >= 0.f) ? e2 : 0.2f * e2;
                e3 = (e3 >= 0.f) ? e3 : 0.2f * e3;
                const float m  = fmaxf(e1, fmaxf(e2, e3));
                const float x1 = expf(e1 - m), x2 = expf(e2 - m), x3 = expf(e3 - m);
                const float inv = 1.f / (x1 + x2 + x3);
                const float agg = (x1 * s_h[1][t] + x2 * s_h[2][t] + x3 * s_h[3][t]) * inv;
                out[(size_t)(nb + j) * E + t] = fmaxf(s_h[0][t] + agg, 0.f);
            }
        }

        // protect buffer bsel^1... and all LDS scratch before next iteration
        asm volatile("s_waitcnt lgkmcnt(0)" ::: "memory");
        __builtin_amdgcn_s_barrier();
    }
}

extern "C" void kernel_launch(void* const* d_in, const int* in_sizes, int n_in,
                              void* d_out, int out_size, void* d_ws, size_t ws_size,
                              hipStream_t stream) {
    const float* features = (const float*)d_in[0];
    const int*   nodes    = (const int*)  d_in[1];
    const int*   neigh1   = (const int*)  d_in[2];
    const int*   neigh2   = (const int*)  d_in[3];
    const int*   neigh3   = (const int*)  d_in[4];
    const float* weight   = (const float*)d_in[5];
    const float* avec     = (const float*)d_in[6];
    float*       out      = (float*)d_out;

    const bool have_norms = ws_size >= (size_t)NTOTAL * sizeof(float);
    if (have_norms) {
        float* invn = (float*)d_ws;
        norms_kernel<<<(NTOTAL + 3) / 4, 256, 0, stream>>>(features, invn);
        interagg_fused<true><<<NNODES / NPB, 256, 0, stream>>>(
            features, nodes, neigh1, neigh2, neigh3, weight, avec, invn, out);
    } else {
        interagg_fused<false><<<NNODES / NPB, 256, 0, stream>>>(
            features, nodes, neigh1, neigh2, neigh3, weight, avec, nullptr, out);
    }
}